// Round 2
// 232.542 us; speedup vs baseline: 1.0230x; 1.0230x over previous
//
#include <hip/hip_runtime.h>

typedef __attribute__((ext_vector_type(8))) short s16x8;   // 8 bf16 MFMA A/B frag
typedef __attribute__((ext_vector_type(4))) short s16x4;
typedef __attribute__((ext_vector_type(4))) float f32x4;   // MFMA C/D frag

#define ST 72   // LDS row stride in shorts: 144 B
#define MFMA __builtin_amdgcn_mfma_f32_16x16x32_bf16

__device__ __forceinline__ short f2bf(float f) {
    unsigned u = __builtin_bit_cast(unsigned, f);
    u += 0x7FFFu + ((u >> 16) & 1u);   // RTNE
    return (short)(u >> 16);
}
__device__ __forceinline__ s16x8 cvt8(f32x4 a, f32x4 b) {
    s16x8 r = { f2bf(a.x), f2bf(a.y), f2bf(a.z), f2bf(a.w),
                f2bf(b.x), f2bf(b.y), f2bf(b.z), f2bf(b.w) };
    return r;
}
__device__ __forceinline__ s16x4 cvt4(f32x4 a) {
    s16x4 r = { f2bf(a.x), f2bf(a.y), f2bf(a.z), f2bf(a.w) };
    return r;
}

// Wave-per-batch, zero-barrier design.
// MFMA(X,Y,acc) computes C[xrow][yrow], xrow = 16*xt + 4q + r (r = acc comp),
// yrow = 16*yt + col, contraction k = 8q + i; X and Y frags share the layout
// frag = M[16*t + col][8q+i (+32)] read as 8 consecutive shorts.
__global__ __launch_bounds__(256, 2) void sam3e_v3(
    const float* __restrict__ F, const float* __restrict__ Kw,
    const float* __restrict__ Qw, float* __restrict__ out)
{
    // per-wave private buffers: [w][0] = A^T (rows d, cols m, column-swizzled),
    //                           [w][1] = KF then S (row-major [n][e] / [n][m])
    __shared__ __align__(16) short lds[4][2][64 * ST];   // 73728 B -> 2 blocks/CU

    const int tid  = threadIdx.x;
    const int w    = tid >> 6;
    const int lane = tid & 63;
    const int col  = lane & 15;
    const int q    = lane >> 4;

    short* sAT = &lds[w][0][0];
    short* sKS = &lds[w][1][0];

    // ---- resident weight X-frags (no LDS, no barrier; L2-hot after first waves) ----
    s16x8 kX[4][2], qX[4][2];
    #pragma unroll
    for (int t = 0; t < 4; ++t) {
        const float* kr = Kw + (16*t + col)*64 + 8*q;
        const float* qr = Qw + (16*t + col)*64 + 8*q;
        #pragma unroll
        for (int h = 0; h < 2; ++h) {
            kX[t][h] = cvt8(*(const f32x4*)(kr + 32*h), *(const f32x4*)(kr + 32*h + 4));
            qX[t][h] = cvt8(*(const f32x4*)(qr + 32*h), *(const f32x4*)(qr + 32*h + 4));
        }
    }

    const f32x4 z4 = {0.f, 0.f, 0.f, 0.f};
    const int gw = blockIdx.x * 4 + w;    // global wave id; 2048 waves, 4 batches each

    #pragma unroll 1
    for (int it = 0; it < 4; ++it) {
        const int b = gw * 4 + it;
        const float* Fb = F   + (size_t)b * 3200;
        float*       Ob = out + (size_t)b * 3200;

        // ---- load F rows -> A X-frags (regs) + stage swizzled A^T ----
        // sAT swizzle: A[m][d] stored at sAT[d*ST + (m ^ (((d>>3)&3)<<3))].
        // Writer lanes have (d>>3)&3 == q -> write banks XOR'd by 4q (conflict-free).
        s16x8 aX[4][2];
        #pragma unroll
        for (int t = 0; t < 4; ++t) {
            const int n = 16*t + col;
            f32x4 v0 = z4, v1 = z4, v2 = z4, v3 = z4;
            if (n < 50) {
                const f32x4* Fr = (const f32x4*)(Fb + n*64 + 8*q);
                v0 = Fr[0]; v1 = Fr[1]; v2 = Fr[8]; v3 = Fr[9];
            }
            aX[t][0] = cvt8(v0, v1);      // k = d in [8q, 8q+7]
            aX[t][1] = cvt8(v2, v3);      // k = d in [32+8q, 32+8q+7]
            const int mc = n ^ (q << 3);  // swizzled column
            short h0[8] = { f2bf(v0.x), f2bf(v0.y), f2bf(v0.z), f2bf(v0.w),
                            f2bf(v1.x), f2bf(v1.y), f2bf(v1.z), f2bf(v1.w) };
            short h1[8] = { f2bf(v2.x), f2bf(v2.y), f2bf(v2.z), f2bf(v2.w),
                            f2bf(v3.x), f2bf(v3.y), f2bf(v3.z), f2bf(v3.w) };
            #pragma unroll
            for (int i = 0; i < 8; ++i) {
                sAT[(8*q + i)*ST + mc]      = h0[i];
                sAT[(32 + 8*q + i)*ST + mc] = h1[i];
            }
        }

        // ---- step 1 (swapped): KF^T = Kw @ A^T -> lane holds KF[n'][4 consec e]
        //      -> b64 stores of KF row-major [n][e] ----
        #pragma unroll
        for (int et = 0; et < 4; ++et) {
            #pragma unroll
            for (int nt = 0; nt < 4; ++nt) {
                f32x4 acc = z4;
                acc = MFMA(kX[et][0], aX[nt][0], acc, 0, 0, 0);
                acc = MFMA(kX[et][1], aX[nt][1], acc, 0, 0, 0);
                *(s16x4*)&sKS[(16*nt + col)*ST + 16*et + 4*q] = cvt4(acc);
            }
        }

        // ---- step 2 (swapped): S^T = KF @ A^T; read KF X-frags first, then
        //      overwrite sKS with S [n][m] (b64 stores) ----
        s16x8 fK[4][2];
        #pragma unroll
        for (int mt = 0; mt < 4; ++mt) {
            fK[mt][0] = *(const s16x8*)&sKS[(16*mt + col)*ST + 8*q];
            fK[mt][1] = *(const s16x8*)&sKS[(16*mt + col)*ST + 32 + 8*q];
        }
        #pragma unroll
        for (int mt = 0; mt < 4; ++mt) {
            #pragma unroll
            for (int nt = 0; nt < 4; ++nt) {
                f32x4 acc = z4;
                acc = MFMA(fK[mt][0], aX[nt][0], acc, 0, 0, 0);
                acc = MFMA(fK[mt][1], aX[nt][1], acc, 0, 0, 0);
                *(s16x4*)&sKS[(16*nt + col)*ST + 16*mt + 4*q] = cvt4(acc);
            }
        }

        // ---- step 3: T^T = A^T @ S^T (X from sAT, Y = S rows);
        //      Q^T = Qw @ A^T (all-register); fused f32x4 epilogue ----
        s16x8 yS[4][2];
        #pragma unroll
        for (int nt = 0; nt < 4; ++nt) {
            yS[nt][0] = *(const s16x8*)&sKS[(16*nt + col)*ST + 8*q];
            yS[nt][1] = *(const s16x8*)&sKS[(16*nt + col)*ST + 32 + 8*q];
        }
        #pragma unroll
        for (int dt = 0; dt < 4; ++dt) {
            const int drow = 16*dt + col;
            const int sw   = (drow >> 3) & 3;   // un-swizzle block index
            const s16x8 xA0 = *(const s16x8*)&sAT[drow*ST + 8*(q ^ sw)];        // m in [8q,8q+7]
            const s16x8 xA1 = *(const s16x8*)&sAT[drow*ST + 8*((q ^ sw) + 4)];  // m in [32+...]
            #pragma unroll
            for (int nt = 0; nt < 4; ++nt) {
                f32x4 tacc = z4, qacc = z4;
                tacc = MFMA(xA0, yS[nt][0], tacc, 0, 0, 0);
                tacc = MFMA(xA1, yS[nt][1], tacc, 0, 0, 0);
                qacc = MFMA(qX[dt][0], aX[nt][0], qacc, 0, 0, 0);
                qacc = MFMA(qX[dt][1], aX[nt][1], qacc, 0, 0, 0);
                const int n = 16*nt + col;
                if (n < 50) {
                    const int d0 = 16*dt + 4*q;
                    const f32x4 Fv = *(const f32x4*)(Fb + n*64 + d0);
                    f32x4 o;
                    o.x = Fv.x * tacc.x + qacc.x;
                    o.y = Fv.y * tacc.y + qacc.y;
                    o.z = Fv.z * tacc.z + qacc.z;
                    o.w = Fv.w * tacc.w + qacc.w;
                    *(f32x4*)(Ob + n*64 + d0) = o;
                }
            }
        }
        // no barrier: wave-private buffers; per-wave DS ordering suffices.
    }
}

extern "C" void kernel_launch(void* const* d_in, const int* in_sizes, int n_in,
                              void* d_out, int out_size, void* d_ws, size_t ws_size,
                              hipStream_t stream) {
    const float* F  = (const float*)d_in[0];   // [8192,50,64]
    const float* Kw = (const float*)d_in[1];   // [64,64]
    const float* Qw = (const float*)d_in[2];   // [64,64]
    float* out = (float*)d_out;
    // 512 blocks x 4 waves = 2048 waves, 4 batches/wave = 8192; 2 blocks/CU
    sam3e_v3<<<512, 256, 0, stream>>>(F, Kw, Qw, out);
}